// Round 2
// baseline (1474.881 us; speedup 1.0000x reference)
//
#include <hip/hip_runtime.h>
#include <math.h>

// ---------- types ----------
typedef __bf16 bf16x8 __attribute__((ext_vector_type(8)));
typedef float  f32x4  __attribute__((ext_vector_type(4)));

__device__ __forceinline__ float bf2f(unsigned short u) {
    union { unsigned int i; float f; } v; v.i = ((unsigned int)u) << 16; return v.f;
}
__device__ __forceinline__ unsigned short f2bf(float f) {
    union { float f; unsigned int i; } v; v.f = f;
    unsigned int x = v.i;
    unsigned int r = (x + 0x7FFFu + ((x >> 16) & 1u)) >> 16;
    return (unsigned short)r;
}
__device__ __forceinline__ uint4 pack8(float4 a, float4 b) {
    uint4 r;
    r.x = (unsigned)f2bf(a.x) | ((unsigned)f2bf(a.y) << 16);
    r.y = (unsigned)f2bf(a.z) | ((unsigned)f2bf(a.w) << 16);
    r.z = (unsigned)f2bf(b.x) | ((unsigned)f2bf(b.y) << 16);
    r.w = (unsigned)f2bf(b.z) | ((unsigned)f2bf(b.w) << 16);
    return r;
}

// ---------- GEMM: Out[m,n] = sum_k A[m,k] * Bw[n,k]  (+ optional f32 residual) ----------
// A: M x K row-major (f32 or bf16). Bw: N x K row-major (f32 or bf16). f32 accumulate via bf16 MFMA.
// Tile 128x128x32. 256 threads = 4 waves in 2x2, each wave 64x64 = 4x4 MFMA 16x16 tiles.
template <bool A_F32, bool B_F32, bool OUT_F32, bool RESID>
__global__ __launch_bounds__(256)
void gemm_bt(const void* __restrict__ Ap, const void* __restrict__ Bp,
             void* __restrict__ Outp, const float* __restrict__ Resid,
             int M, int N, int K) {
    __shared__ __align__(16) __bf16 As[128 * 40];   // pad 32 -> 40 (2-way LDS conflicts only)
    __shared__ __align__(16) __bf16 Bs[128 * 40];

    const int tid  = threadIdx.x;
    const int m0   = blockIdx.y * 128;
    const int n0   = blockIdx.x * 128;
    const int wave = tid >> 6, lane = tid & 63;
    const int wm   = (wave & 1) * 64, wn = (wave >> 1) * 64;
    const int lr   = lane & 15, q = lane >> 4;

    f32x4 acc[4][4] = {};

    for (int k0 = 0; k0 < K; k0 += 32) {
        #pragma unroll
        for (int c = tid; c < 512; c += 256) {
            int r = c >> 2, k8 = (c & 3) << 3;
            uint4 pa;
            if (A_F32) {
                const float* src = (const float*)Ap + (size_t)(m0 + r) * K + k0 + k8;
                pa = pack8(*(const float4*)src, *(const float4*)(src + 4));
            } else {
                pa = *(const uint4*)((const unsigned short*)Ap + (size_t)(m0 + r) * K + k0 + k8);
            }
            *(uint4*)(As + r * 40 + k8) = pa;

            int n = n0 + r;
            uint4 pb = make_uint4(0u, 0u, 0u, 0u);
            if (n < N) {
                if (B_F32) {
                    const float* src = (const float*)Bp + (size_t)n * K + k0 + k8;
                    pb = pack8(*(const float4*)src, *(const float4*)(src + 4));
                } else {
                    pb = *(const uint4*)((const unsigned short*)Bp + (size_t)n * K + k0 + k8);
                }
            }
            *(uint4*)(Bs + r * 40 + k8) = pb;
        }
        __syncthreads();

        bf16x8 af[4], bfr[4];
        #pragma unroll
        for (int t = 0; t < 4; ++t) {
            af[t]  = *(const bf16x8*)(As + (wm + t * 16 + lr) * 40 + q * 8);
            bfr[t] = *(const bf16x8*)(Bs + (wn + t * 16 + lr) * 40 + q * 8);
        }
        #pragma unroll
        for (int ti = 0; ti < 4; ++ti)
            #pragma unroll
            for (int tj = 0; tj < 4; ++tj)
                acc[ti][tj] = __builtin_amdgcn_mfma_f32_16x16x32_bf16(af[ti], bfr[tj], acc[ti][tj], 0, 0, 0);
        __syncthreads();
    }

    // epilogue: D row m = quad*4 + reg, col n = lane&15
    #pragma unroll
    for (int ti = 0; ti < 4; ++ti) {
        #pragma unroll
        for (int r = 0; r < 4; ++r) {
            int m = m0 + wm + ti * 16 + q * 4 + r;
            #pragma unroll
            for (int tj = 0; tj < 4; ++tj) {
                int n = n0 + wn + tj * 16 + lr;
                if (n < N) {
                    float v = acc[ti][tj][r];
                    if (RESID) v += Resid[(size_t)m * N + n];
                    if (OUT_F32) ((float*)Outp)[(size_t)m * N + n] = v;
                    else ((unsigned short*)Outp)[(size_t)m * N + n] = f2bf(v);
                }
            }
        }
    }
}

// ---------- causal depthwise conv(4) + silu over xBC channels ----------
// zx: (8192, 3352) bf16, xBC = cols [1536, 3328). out: (8192, 1792) f32.
__global__ void conv_silu_kernel(const unsigned short* __restrict__ zx,
                                 const float* __restrict__ cw,
                                 const float* __restrict__ cb,
                                 float* __restrict__ convo) {
    int idx = blockIdx.x * 256 + threadIdx.x;
    if (idx >= 8192 * 1792) return;
    int c = idx % 1792;
    int row = idx / 1792;
    int l = row & 2047;                     // L = 2048
    float acc = cb[c];
    #pragma unroll
    for (int k = 0; k < 4; ++k) {
        int dl = 3 - k;
        if (l >= dl)
            acc += bf2f(zx[(size_t)(row - dl) * 3352 + 1536 + c]) * cw[c * 4 + k];
    }
    convo[idx] = acc / (1.f + expf(-acc));  // silu
}

// ---------- dt in full f32: dt_raw = x_row . W_in[3328+h], dt = softplus(+bias), dA = exp(dt*A) ----------
__global__ __launch_bounds__(64)
void dt_kernel(const float* __restrict__ x, const float* __restrict__ w_in,
               const float* __restrict__ dt_bias, const float* __restrict__ A_log,
               float* __restrict__ dtA, float* __restrict__ dAA) {
    int row = blockIdx.x;
    int lane = threadIdx.x;
    float xv[12];
    #pragma unroll
    for (int i = 0; i < 12; ++i) xv[i] = x[(size_t)row * 768 + i * 64 + lane];
    for (int h = 0; h < 24; ++h) {
        const float* w = w_in + (size_t)(3328 + h) * 768;
        float acc = 0.f;
        #pragma unroll
        for (int i = 0; i < 12; ++i) acc += xv[i] * w[i * 64 + lane];
        #pragma unroll
        for (int m = 1; m < 64; m <<= 1) acc += __shfl_xor(acc, m);
        if (lane == 0) {
            float v = acc + dt_bias[h];
            float dt = (v > 20.f) ? v : log1pf(expf(v));
            float A = -expf(A_log[h]);
            dtA[(size_t)row * 24 + h] = dt;
            dAA[(size_t)row * 24 + h] = expf(dt * A);
        }
    }
}

// ---------- selective scan ----------
// 384 blocks x 256 threads. Block -> (b,h, p-group of 16). Wave handles 4 p; 16 lanes/p, 8 n-states/lane.
__global__ __launch_bounds__(256)
void scan_kernel(const float* __restrict__ cv,
                 const float* __restrict__ dtA,
                 const float* __restrict__ dAA,
                 const float* __restrict__ Dh,
                 float* __restrict__ yb) {
    int blk = blockIdx.x;
    int bh = blk >> 2, pg = blk & 3;
    int b = bh / 24, h = bh % 24;
    int wave = threadIdx.x >> 6, lane = threadIdx.x & 63;
    int p = pg * 16 + wave * 4 + (lane >> 4);
    int lr = lane & 15;

    const float* base = cv + (size_t)b * 2048 * 1792;
    const float* xp  = base + h * 64 + p;
    const float* bp  = base + 1536 + lr * 8;
    const float* cp  = base + 1664 + lr * 8;
    const float* dtp = dtA + (size_t)b * 2048 * 24 + h;
    const float* dAp = dAA + (size_t)b * 2048 * 24 + h;
    float Dv = Dh[h];
    float* yp = yb + (size_t)b * 2048 * 1536 + h * 64 + p;

    float s[8];
    #pragma unroll
    for (int j = 0; j < 8; ++j) s[j] = 0.f;

    for (int t = 0; t < 2048; ++t) {
        float  xv = xp[(size_t)t * 1792];
        float4 b0 = *(const float4*)(bp + (size_t)t * 1792);
        float4 b1 = *(const float4*)(bp + (size_t)t * 1792 + 4);
        float4 c0 = *(const float4*)(cp + (size_t)t * 1792);
        float4 c1 = *(const float4*)(cp + (size_t)t * 1792 + 4);
        float dtv = dtp[t * 24];
        float dAv = dAp[t * 24];
        float dtx = dtv * xv;
        float bb[8] = {b0.x, b0.y, b0.z, b0.w, b1.x, b1.y, b1.z, b1.w};
        float cc[8] = {c0.x, c0.y, c0.z, c0.w, c1.x, c1.y, c1.z, c1.w};
        float acc = 0.f;
        #pragma unroll
        for (int j = 0; j < 8; ++j) {
            s[j] = s[j] * dAv + dtx * bb[j];
            acc += s[j] * cc[j];
        }
        acc += __shfl_xor(acc, 1);
        acc += __shfl_xor(acc, 2);
        acc += __shfl_xor(acc, 4);
        acc += __shfl_xor(acc, 8);
        if (lr == 0) yp[(size_t)t * 1536] = acc + Dv * xv;
    }
}

// ---------- gated RMSNorm: u = y * silu(z); out = u * rsqrt(mean(u^2)+eps) * w -> bf16 ----------
__global__ __launch_bounds__(256)
void norm_kernel(const float* __restrict__ yb,
                 const unsigned short* __restrict__ zx,
                 const float* __restrict__ nw,
                 unsigned short* __restrict__ yn) {
    int row = blockIdx.x;
    const float* yr = yb + (size_t)row * 1536;
    const unsigned short* zr = zx + (size_t)row * 3352;
    int tid = threadIdx.x;
    float u[6];
    float ss = 0.f;
    #pragma unroll
    for (int i = 0; i < 6; ++i) {
        int c = tid + i * 256;
        float z = bf2f(zr[c]);
        float uu = yr[c] * (z / (1.f + expf(-z)));
        u[i] = uu;
        ss += uu * uu;
    }
    #pragma unroll
    for (int m = 1; m < 64; m <<= 1) ss += __shfl_xor(ss, m);
    __shared__ float red[4];
    if ((tid & 63) == 0) red[tid >> 6] = ss;
    __syncthreads();
    float tot = red[0] + red[1] + red[2] + red[3];
    float inv = rsqrtf(tot * (1.f / 1536.f) + 1e-5f);
    #pragma unroll
    for (int i = 0; i < 6; ++i) {
        int c = tid + i * 256;
        yn[(size_t)row * 1536 + c] = f2bf(u[i] * inv * nw[c]);
    }
}

// ---------- launch ----------
extern "C" void kernel_launch(void* const* d_in, const int* in_sizes, int n_in,
                              void* d_out, int out_size, void* d_ws, size_t ws_size,
                              hipStream_t stream) {
    const float* x       = (const float*)d_in[0]; // (4,2048,768)
    const float* w_in    = (const float*)d_in[1]; // (3352,768)
    const float* conv_w  = (const float*)d_in[2]; // (1792,4)
    const float* conv_b  = (const float*)d_in[3]; // (1792,)
    const float* dt_bias = (const float*)d_in[4]; // (24,)
    const float* A_log   = (const float*)d_in[5]; // (24,)
    const float* Dp      = (const float*)d_in[6]; // (24,)
    const float* nw      = (const float*)d_in[7]; // (1536,)
    const float* w_out   = (const float*)d_in[8]; // (768,1536)
    float* out = (float*)d_out;                   // (4,2048,768)

    char* ws = (char*)d_ws;
    const size_t off_zx   = 0;                            // 8192*3352 bf16 = 54,919,168 B
    const size_t off_conv = off_zx + 54919168;            // 8192*1792 f32  = 58,720,256 B
    const size_t off_dt   = off_conv + 58720256;          // 8192*24 f32    =    786,432 B
    const size_t off_dA   = off_dt + 786432;
    const size_t off_y    = off_dA + 786432;              // 8192*1536 f32  = 50,331,648 B
    const size_t off_yn   = off_y + 50331648;             // 8192*1536 bf16 = 25,165,824 B

    unsigned short* zx = (unsigned short*)(ws + off_zx);
    float* cv  = (float*)(ws + off_conv);
    float* dtA = (float*)(ws + off_dt);
    float* dAA = (float*)(ws + off_dA);
    float* yb  = (float*)(ws + off_y);
    unsigned short* yn = (unsigned short*)(ws + off_yn);

    // 1. in_proj: zxbcdt = x @ W_in^T   (M=8192, N=3352, K=768), f32 in -> bf16 out
    gemm_bt<true, true, false, false><<<dim3(27, 64), 256, 0, stream>>>(x, w_in, zx, nullptr, 8192, 3352, 768);
    // 2. causal depthwise conv + silu
    conv_silu_kernel<<<57344, 256, 0, stream>>>(zx, conv_w, conv_b, cv);
    // 3. dt / dA in full f32 (dt is the exp-sensitive path)
    dt_kernel<<<8192, 64, 0, stream>>>(x, w_in, dt_bias, A_log, dtA, dAA);
    // 4. selective scan (+ D skip)
    scan_kernel<<<384, 256, 0, stream>>>(cv, dtA, dAA, Dp, yb);
    // 5. gated RMSNorm -> bf16
    norm_kernel<<<8192, 256, 0, stream>>>(yb, zx, nw, yn);
    // 6. out_proj + residual   (M=8192, N=768, K=1536), A bf16, B f32, out f32
    gemm_bt<false, true, true, true><<<dim3(6, 64), 256, 0, stream>>>(yn, w_out, out, x, 8192, 768, 1536);
}

// Round 3
// 1178.610 us; speedup vs baseline: 1.2514x; 1.2514x over previous
//
#include <hip/hip_runtime.h>
#include <math.h>

// ---------- types ----------
typedef __bf16 bf16x8 __attribute__((ext_vector_type(8)));
typedef float  f32x4  __attribute__((ext_vector_type(4)));

#define QCHUNK 128
#define NCHUNK 16

__device__ __forceinline__ float bf2f(unsigned short u) {
    union { unsigned int i; float f; } v; v.i = ((unsigned int)u) << 16; return v.f;
}
__device__ __forceinline__ unsigned short f2bf(float f) {
    union { float f; unsigned int i; } v; v.f = f;
    unsigned int x = v.i;
    unsigned int r = (x + 0x7FFFu + ((x >> 16) & 1u)) >> 16;
    return (unsigned short)r;
}
__device__ __forceinline__ uint4 pack8(float4 a, float4 b) {
    uint4 r;
    r.x = (unsigned)f2bf(a.x) | ((unsigned)f2bf(a.y) << 16);
    r.y = (unsigned)f2bf(a.z) | ((unsigned)f2bf(a.w) << 16);
    r.z = (unsigned)f2bf(b.x) | ((unsigned)f2bf(b.y) << 16);
    r.w = (unsigned)f2bf(b.z) | ((unsigned)f2bf(b.w) << 16);
    return r;
}

// ---------- GEMM: Out[m,n] = sum_k A[m,k] * Bw[n,k]  (+ optional f32 residual) ----------
// Tile 128x128x32. 256 threads = 4 waves in 2x2, each wave 64x64 = 4x4 MFMA 16x16 tiles.
template <bool A_F32, bool B_F32, bool OUT_F32, bool RESID>
__global__ __launch_bounds__(256)
void gemm_bt(const void* __restrict__ Ap, const void* __restrict__ Bp,
             void* __restrict__ Outp, const float* __restrict__ Resid,
             int M, int N, int K, int lda, int ldb) {
    __shared__ __align__(16) __bf16 As[128 * 40];   // pad 32 -> 40 (2-way LDS conflicts only)
    __shared__ __align__(16) __bf16 Bs[128 * 40];

    const int tid  = threadIdx.x;
    const int m0   = blockIdx.y * 128;
    const int n0   = blockIdx.x * 128;
    const int wave = tid >> 6, lane = tid & 63;
    const int wm   = (wave & 1) * 64, wn = (wave >> 1) * 64;
    const int lr   = lane & 15, q = lane >> 4;

    f32x4 acc[4][4] = {};

    for (int k0 = 0; k0 < K; k0 += 32) {
        #pragma unroll
        for (int c = tid; c < 512; c += 256) {
            int r = c >> 2, k8 = (c & 3) << 3;
            uint4 pa;
            if (A_F32) {
                const float* src = (const float*)Ap + (size_t)(m0 + r) * lda + k0 + k8;
                pa = pack8(*(const float4*)src, *(const float4*)(src + 4));
            } else {
                pa = *(const uint4*)((const unsigned short*)Ap + (size_t)(m0 + r) * lda + k0 + k8);
            }
            *(uint4*)(As + r * 40 + k8) = pa;

            int n = n0 + r;
            uint4 pb = make_uint4(0u, 0u, 0u, 0u);
            if (n < N) {
                if (B_F32) {
                    const float* src = (const float*)Bp + (size_t)n * ldb + k0 + k8;
                    pb = pack8(*(const float4*)src, *(const float4*)(src + 4));
                } else {
                    pb = *(const uint4*)((const unsigned short*)Bp + (size_t)n * ldb + k0 + k8);
                }
            }
            *(uint4*)(Bs + r * 40 + k8) = pb;
        }
        __syncthreads();

        bf16x8 af[4], bfr[4];
        #pragma unroll
        for (int t = 0; t < 4; ++t) {
            af[t]  = *(const bf16x8*)(As + (wm + t * 16 + lr) * 40 + q * 8);
            bfr[t] = *(const bf16x8*)(Bs + (wn + t * 16 + lr) * 40 + q * 8);
        }
        #pragma unroll
        for (int ti = 0; ti < 4; ++ti)
            #pragma unroll
            for (int tj = 0; tj < 4; ++tj)
                acc[ti][tj] = __builtin_amdgcn_mfma_f32_16x16x32_bf16(af[ti], bfr[tj], acc[ti][tj], 0, 0, 0);
        __syncthreads();
    }

    // epilogue: D row m = quad*4 + reg, col n = lane&15
    #pragma unroll
    for (int ti = 0; ti < 4; ++ti) {
        #pragma unroll
        for (int r = 0; r < 4; ++r) {
            int m = m0 + wm + ti * 16 + q * 4 + r;
            #pragma unroll
            for (int tj = 0; tj < 4; ++tj) {
                int n = n0 + wn + tj * 16 + lr;
                if (n < N) {
                    float v = acc[ti][tj][r];
                    if (RESID) v += Resid[(size_t)m * N + n];
                    if (OUT_F32) ((float*)Outp)[(size_t)m * N + n] = v;
                    else ((unsigned short*)Outp)[(size_t)m * N + n] = f2bf(v);
                }
            }
        }
    }
}

// ---------- causal depthwise conv(4) + silu over xBC channels ----------
__global__ void conv_silu_kernel(const unsigned short* __restrict__ zx,
                                 const float* __restrict__ cw,
                                 const float* __restrict__ cb,
                                 float* __restrict__ convo) {
    int idx = blockIdx.x * 256 + threadIdx.x;
    if (idx >= 8192 * 1792) return;
    int c = idx % 1792;
    int row = idx / 1792;
    int l = row & 2047;                     // L = 2048
    float acc = cb[c];
    #pragma unroll
    for (int k = 0; k < 4; ++k) {
        int dl = 3 - k;
        if (l >= dl)
            acc += bf2f(zx[(size_t)(row - dl) * 3352 + 1536 + c]) * cw[c * 4 + k];
    }
    convo[idx] = acc / (1.f + expf(-acc));  // silu
}

// ---------- dt in full f32: dt_raw = x_row . W_in[3328+h], dt = softplus(+bias), dA = exp(dt*A) ----------
__global__ __launch_bounds__(64)
void dt_kernel(const float* __restrict__ x, const float* __restrict__ w_in,
               const float* __restrict__ dt_bias, const float* __restrict__ A_log,
               float* __restrict__ dtA, float* __restrict__ dAA) {
    int row = blockIdx.x;
    int lane = threadIdx.x;
    float xv[12];
    #pragma unroll
    for (int i = 0; i < 12; ++i) xv[i] = x[(size_t)row * 768 + i * 64 + lane];
    for (int h = 0; h < 24; ++h) {
        const float* w = w_in + (size_t)(3328 + h) * 768;
        float acc = 0.f;
        #pragma unroll
        for (int i = 0; i < 12; ++i) acc += xv[i] * w[i * 64 + lane];
        #pragma unroll
        for (int m = 1; m < 64; m <<= 1) acc += __shfl_xor(acc, m);
        if (lane == 0) {
            float v = acc + dt_bias[h];
            float dt = (v > 20.f) ? v : log1pf(expf(v));
            float A = -expf(A_log[h]);
            dtA[(size_t)row * 24 + h] = dt;
            dAA[(size_t)row * 24 + h] = expf(dt * A);
        }
    }
}

// ---------- pass A: per-chunk local scan (s starts at 0), writes y_local, s_loc (bf16), P ----------
// grid: bh(96) x pg(4) x c(16) = 6144 blocks, 256 threads. Wave = 4 p, 16 lanes/p, 8 n/lane.
__global__ __launch_bounds__(256)
void scan_local_kernel(const float* __restrict__ cv,
                       const float* __restrict__ dtA,
                       const float* __restrict__ dAA,
                       const float* __restrict__ Dh,
                       float* __restrict__ yb,
                       unsigned short* __restrict__ sst,
                       float* __restrict__ Pbuf) {
    int blk = blockIdx.x;
    int c  = blk & 15;
    int pg = (blk >> 4) & 3;
    int bh = blk >> 6;
    int b = bh / 24, h = bh % 24;
    int wave = threadIdx.x >> 6, lane = threadIdx.x & 63;
    int p = pg * 16 + wave * 4 + (lane >> 4);
    int lr = lane & 15;
    int t0 = c * QCHUNK;

    const float* base = cv + ((size_t)b * 2048 + t0) * 1792;
    const float* xp  = base + h * 64 + p;
    const float* bp  = base + 1536 + lr * 8;
    const float* cp  = base + 1664 + lr * 8;
    const float* dtp = dtA + ((size_t)b * 2048 + t0) * 24 + h;
    const float* dAp = dAA + ((size_t)b * 2048 + t0) * 24 + h;
    float Dv = Dh[h];
    float* yp = yb + ((size_t)b * 2048 + t0) * 1536 + h * 64 + p;

    float s[8];
    #pragma unroll
    for (int j = 0; j < 8; ++j) s[j] = 0.f;
    float dAprod = 1.f;

    for (int t = 0; t < QCHUNK; ++t) {
        float  xv = xp[(size_t)t * 1792];
        float4 b0 = *(const float4*)(bp + (size_t)t * 1792);
        float4 b1 = *(const float4*)(bp + (size_t)t * 1792 + 4);
        float4 c0 = *(const float4*)(cp + (size_t)t * 1792);
        float4 c1 = *(const float4*)(cp + (size_t)t * 1792 + 4);
        float dtv = dtp[t * 24];
        float dAv = dAp[t * 24];
        dAprod *= dAv;
        float dtx = dtv * xv;
        float bb[8] = {b0.x, b0.y, b0.z, b0.w, b1.x, b1.y, b1.z, b1.w};
        float cc[8] = {c0.x, c0.y, c0.z, c0.w, c1.x, c1.y, c1.z, c1.w};
        float acc = 0.f;
        #pragma unroll
        for (int j = 0; j < 8; ++j) {
            s[j] = s[j] * dAv + dtx * bb[j];
            acc += s[j] * cc[j];
        }
        acc += __shfl_xor(acc, 1);
        acc += __shfl_xor(acc, 2);
        acc += __shfl_xor(acc, 4);
        acc += __shfl_xor(acc, 8);
        if (lr == 0) yp[(size_t)t * 1536] = acc + Dv * xv;
    }

    // write local final state (bf16): layout [bh][c][p][n]
    unsigned short* sp = sst + ((((size_t)bh * NCHUNK + c) * 64 + p) * 128) + lr * 8;
    *(uint4*)sp = pack8(make_float4(s[0], s[1], s[2], s[3]),
                        make_float4(s[4], s[5], s[6], s[7]));
    if (threadIdx.x == 0 && pg == 0) Pbuf[bh * NCHUNK + c] = dAprod;
}

// ---------- pass B: in-place chunk-state combine: s_in(c) = P(c-1)*s_in(c-1) + s_loc(c-1) ----------
// grid: 3072 blocks x 256 threads; thread owns one (bh, p, n) across all chunks.
__global__ __launch_bounds__(256)
void combine_kernel(unsigned short* __restrict__ sst, const float* __restrict__ Pbuf) {
    int flat = blockIdx.x * 256 + threadIdx.x;   // 96 * 8192 = 786432
    int bh = flat >> 13;
    int pn = flat & 8191;
    unsigned short* sb = sst + (size_t)bh * NCHUNK * 8192 + pn;
    const float* Pb = Pbuf + bh * NCHUNK;
    float s = 0.f;
    #pragma unroll
    for (int c = 0; c < NCHUNK; ++c) {
        unsigned short* q = sb + (size_t)c * 8192;
        float tmp = bf2f(*q);   // s_loc(c)
        *q = f2bf(s);           // becomes s_in(c)
        s = Pb[c] * s + tmp;
    }
}

// ---------- pass C: inter-chunk: y_t += Acum(t) * (C_t . s_in) ----------
__global__ __launch_bounds__(256)
void scan_inter_kernel(const float* __restrict__ cv,
                       const float* __restrict__ dAA,
                       const unsigned short* __restrict__ sst,
                       float* __restrict__ yb) {
    int blk = blockIdx.x;
    int c  = blk & 15;
    if (c == 0) return;  // s_in(0) == 0
    int pg = (blk >> 4) & 3;
    int bh = blk >> 6;
    int b = bh / 24, h = bh % 24;
    int wave = threadIdx.x >> 6, lane = threadIdx.x & 63;
    int p = pg * 16 + wave * 4 + (lane >> 4);
    int lr = lane & 15;
    int t0 = c * QCHUNK;

    const unsigned short* sp = sst + ((((size_t)bh * NCHUNK + c) * 64 + p) * 128) + lr * 8;
    uint4 pk = *(const uint4*)sp;
    float si[8];
    si[0] = bf2f((unsigned short)(pk.x & 0xFFFF)); si[1] = bf2f((unsigned short)(pk.x >> 16));
    si[2] = bf2f((unsigned short)(pk.y & 0xFFFF)); si[3] = bf2f((unsigned short)(pk.y >> 16));
    si[4] = bf2f((unsigned short)(pk.z & 0xFFFF)); si[5] = bf2f((unsigned short)(pk.z >> 16));
    si[6] = bf2f((unsigned short)(pk.w & 0xFFFF)); si[7] = bf2f((unsigned short)(pk.w >> 16));

    const float* cp  = cv + ((size_t)b * 2048 + t0) * 1792 + 1664 + lr * 8;
    const float* dAp = dAA + ((size_t)b * 2048 + t0) * 24 + h;
    float* yp = yb + ((size_t)b * 2048 + t0) * 1536 + h * 64 + p;

    float Acum = 1.f;
    for (int t = 0; t < QCHUNK; ++t) {
        float dAv = dAp[t * 24];
        Acum *= dAv;
        float4 c0 = *(const float4*)(cp + (size_t)t * 1792);
        float4 c1 = *(const float4*)(cp + (size_t)t * 1792 + 4);
        float cc[8] = {c0.x, c0.y, c0.z, c0.w, c1.x, c1.y, c1.z, c1.w};
        float acc = 0.f;
        #pragma unroll
        for (int j = 0; j < 8; ++j) acc += si[j] * cc[j];
        acc += __shfl_xor(acc, 1);
        acc += __shfl_xor(acc, 2);
        acc += __shfl_xor(acc, 4);
        acc += __shfl_xor(acc, 8);
        if (lr == 0) yp[(size_t)t * 1536] += Acum * acc;
    }
}

// ---------- gated RMSNorm: u = y * silu(z); writes bf16 into zx cols [1536,3072) (xBC region is dead) ----------
__global__ __launch_bounds__(256)
void norm_kernel(const float* __restrict__ yb,
                 unsigned short* __restrict__ zx,
                 const float* __restrict__ nw) {
    int row = blockIdx.x;
    const float* yr = yb + (size_t)row * 1536;
    unsigned short* zr = zx + (size_t)row * 3352;
    int tid = threadIdx.x;
    float u[6];
    float ss = 0.f;
    #pragma unroll
    for (int i = 0; i < 6; ++i) {
        int c = tid + i * 256;
        float z = bf2f(zr[c]);
        float uu = yr[c] * (z / (1.f + expf(-z)));
        u[i] = uu;
        ss += uu * uu;
    }
    #pragma unroll
    for (int m = 1; m < 64; m <<= 1) ss += __shfl_xor(ss, m);
    __shared__ float red[4];
    if ((tid & 63) == 0) red[tid >> 6] = ss;
    __syncthreads();
    float tot = red[0] + red[1] + red[2] + red[3];
    float inv = rsqrtf(tot * (1.f / 1536.f) + 1e-5f);
    #pragma unroll
    for (int i = 0; i < 6; ++i) {
        int c = tid + i * 256;
        zr[1536 + c] = f2bf(u[i] * inv * nw[c]);
    }
}

// ---------- launch ----------
extern "C" void kernel_launch(void* const* d_in, const int* in_sizes, int n_in,
                              void* d_out, int out_size, void* d_ws, size_t ws_size,
                              hipStream_t stream) {
    const float* x       = (const float*)d_in[0]; // (4,2048,768)
    const float* w_in    = (const float*)d_in[1]; // (3352,768)
    const float* conv_w  = (const float*)d_in[2]; // (1792,4)
    const float* conv_b  = (const float*)d_in[3]; // (1792,)
    const float* dt_bias = (const float*)d_in[4]; // (24,)
    const float* A_log   = (const float*)d_in[5]; // (24,)
    const float* Dp      = (const float*)d_in[6]; // (24,)
    const float* nw      = (const float*)d_in[7]; // (1536,)
    const float* w_out   = (const float*)d_in[8]; // (768,1536)
    float* out = (float*)d_out;                   // (4,2048,768)

    char* ws = (char*)d_ws;
    const size_t off_zx   = 0;                       // 8192*3352 bf16 = 54,919,168
    const size_t off_conv = off_zx + 54919168;       // 8192*1792 f32  = 58,720,256
    const size_t off_dt   = off_conv + 58720256;     // 786,432
    const size_t off_dA   = off_dt + 786432;         // 786,432
    const size_t off_y    = off_dA + 786432;         // 8192*1536 f32  = 50,331,648
    const size_t off_sst  = off_y + 50331648;        // 96*16*8192 bf16 = 25,165,824
    const size_t off_P    = off_sst + 25165824;      // 96*16 f32 = 6,144

    unsigned short* zx = (unsigned short*)(ws + off_zx);
    float* cv  = (float*)(ws + off_conv);
    float* dtA = (float*)(ws + off_dt);
    float* dAA = (float*)(ws + off_dA);
    float* yb  = (float*)(ws + off_y);
    unsigned short* sst = (unsigned short*)(ws + off_sst);
    float* Pbuf = (float*)(ws + off_P);

    // 1. in_proj: zxbcdt = x @ W_in^T   (M=8192, N=3352, K=768), f32 in -> bf16 out
    gemm_bt<true, true, false, false><<<dim3(27, 64), 256, 0, stream>>>(x, w_in, zx, nullptr, 8192, 3352, 768, 768, 768);
    // 2. causal depthwise conv + silu
    conv_silu_kernel<<<57344, 256, 0, stream>>>(zx, conv_w, conv_b, cv);
    // 3. dt / dA in full f32
    dt_kernel<<<8192, 64, 0, stream>>>(x, w_in, dt_bias, A_log, dtA, dAA);
    // 4a. chunked scan: local pass
    scan_local_kernel<<<6144, 256, 0, stream>>>(cv, dtA, dAA, Dp, yb, sst, Pbuf);
    // 4b. chunk-state combine (in-place s_loc -> s_in)
    combine_kernel<<<3072, 256, 0, stream>>>(sst, Pbuf);
    // 4c. inter-chunk correction
    scan_inter_kernel<<<6144, 256, 0, stream>>>(cv, dAA, sst, yb);
    // 5. gated RMSNorm -> bf16 into zx cols [1536,3072)
    norm_kernel<<<8192, 256, 0, stream>>>(yb, zx, nw);
    // 6. out_proj + residual (A = normed y, bf16, lda=3352)
    gemm_bt<false, true, true, true><<<dim3(6, 64), 256, 0, stream>>>(zx + 1536, w_out, out, x, 8192, 768, 1536, 3352, 1536);
}